// Round 1
// baseline (3672.162 us; speedup 1.0000x reference)
//
#include <hip/hip_runtime.h>
#include <hip/hip_bf16.h>

// LSTM H=1024, B=256, T=256, C=10.
// Strategy (round 0): one kernel launch per timestep (stream-ordered, no
// inter-WG sync). bf16 MFMA 16x16x32 for the 4-gate GEMM, fp32 master h/c.
// W pre-swizzled into MFMA A-fragment order; h stored in B-fragment order.

#define H 1024
#define B 256
#define T 256
#define NCLS 10

typedef __attribute__((ext_vector_type(8))) short short8;   // 8 bf16
typedef __attribute__((ext_vector_type(4))) float f32x4;

// ---------------- W swizzle: fp32 (H,H) x4 -> bf16 MFMA-A-fragment order ---
// Wsw[((gate*64 + jt)*32 + kk)*512 + lane*8 + i] = W_gate[jt*16 + (lane&15)][kk*32 + (lane>>4)*8 + i]
__global__ __launch_bounds__(256) void prep_swizzle(
    const float* __restrict__ Wgh, const float* __restrict__ Wih,
    const float* __restrict__ Wfh, const float* __restrict__ Woh,
    __hip_bfloat16* __restrict__ Wsw)
{
    int idx = blockIdx.x * 256 + threadIdx.x;          // 0 .. 4M-1
    int i    = idx & 7;
    int lane = (idx >> 3) & 63;
    int kk   = (idx >> 9) & 31;
    int jt   = (idx >> 14) & 63;
    int gate = idx >> 20;
    int j = jt * 16 + (lane & 15);
    int k = kk * 32 + (lane >> 4) * 8 + i;
    const float* W = (gate == 0) ? Wgh : (gate == 1) ? Wih : (gate == 2) ? Wfh : Woh;
    Wsw[idx] = __float2bfloat16(W[j * H + k]);
}

// ---------------- one LSTM timestep ----------------------------------------
// grid 256 WGs x 256 thr. blockIdx: jt = >>2 (16 h-rows), bt = &3 (64 cols).
// wave w = gate w (g,i,f,o). Each wave: 16 rows x 64 cols, K=1024.
__global__ __launch_bounds__(256) void lstm_step(
    const __hip_bfloat16* __restrict__ Wsw,
    const __hip_bfloat16* __restrict__ h_in,    // B-fragment layout, bf16
    __hip_bfloat16* __restrict__ h_out,         // B-fragment layout, bf16
    float* __restrict__ c_state,                // [j*256 + b] fp32
    const float* __restrict__ x,                // (B,T)
    const float* __restrict__ Wgx, const float* __restrict__ Wix,
    const float* __restrict__ Wfx, const float* __restrict__ Wox,
    const float* __restrict__ bg, const float* __restrict__ bi,
    const float* __restrict__ bfv, const float* __restrict__ bo,
    int t, float* __restrict__ h_final)
{
    __shared__ float ldsZ[4][16][64];

    const int lane = threadIdx.x & 63;
    const int wave = threadIdx.x >> 6;
    const int jt = blockIdx.x >> 2;
    const int bt = blockIdx.x & 3;

    const short* wp = (const short*)Wsw + (wave * 64 + jt) * 16384 + lane * 8;
    const short* hp = (const short*)h_in + (bt * 4) * 16384 + lane * 8;

    f32x4 a0 = {0.f, 0.f, 0.f, 0.f};
    f32x4 a1 = a0, a2 = a0, a3 = a0;

#pragma unroll 4
    for (int kk = 0; kk < 32; ++kk) {
        short8 af = *(const short8*)(wp + kk * 512);
        short8 b0 = *(const short8*)(hp + kk * 512);
        short8 b1 = *(const short8*)(hp + 16384 + kk * 512);
        short8 b2 = *(const short8*)(hp + 2 * 16384 + kk * 512);
        short8 b3 = *(const short8*)(hp + 3 * 16384 + kk * 512);
        a0 = __builtin_amdgcn_mfma_f32_16x16x32_bf16(af, b0, a0, 0, 0, 0);
        a1 = __builtin_amdgcn_mfma_f32_16x16x32_bf16(af, b1, a1, 0, 0, 0);
        a2 = __builtin_amdgcn_mfma_f32_16x16x32_bf16(af, b2, a2, 0, 0, 0);
        a3 = __builtin_amdgcn_mfma_f32_16x16x32_bf16(af, b3, a3, 0, 0, 0);
    }

    // C/D layout: col = lane&15, row = (lane>>4)*4 + reg
    const int rowb = (lane >> 4) * 4;
    const int coln = lane & 15;
#pragma unroll
    for (int r = 0; r < 4; ++r) {
        ldsZ[wave][rowb + r][0 * 16 + coln] = a0[r];
        ldsZ[wave][rowb + r][1 * 16 + coln] = a1[r];
        ldsZ[wave][rowb + r][2 * 16 + coln] = a2[r];
        ldsZ[wave][rowb + r][3 * 16 + coln] = a3[r];
    }
    __syncthreads();

    // elementwise: 1024 (m,n) elements, 4 per thread
    for (int e = threadIdx.x; e < 1024; e += 256) {
        int m = e >> 6, n = e & 63;
        int j = jt * 16 + m;
        int b = bt * 64 + n;
        float xv = x[b * T + t];
        float zg = ldsZ[0][m][n] + Wgx[j] * xv + bg[b];
        float zi = ldsZ[1][m][n] + Wix[j] * xv + bi[b];
        float zf = ldsZ[2][m][n] + Wfx[j] * xv + bfv[b];
        float zo = ldsZ[3][m][n] + Wox[j] * xv + bo[b];
        float g  = tanhf(zg);
        float ig = 1.f / (1.f + expf(-zi));
        float fg = 1.f / (1.f + expf(-zf));
        float og = 1.f / (1.f + expf(-zo));
        int cidx = j * B + b;
        float cn = g * ig + c_state[cidx] * fg;
        c_state[cidx] = cn;
        float hn = tanhf(cn) * og;
        // h fragment offset: ((b>>4)*32 + (j>>5))*512 + (((j>>3)&3)*16 + (b&15))*8 + (j&7)
        int ofs = ((b >> 4) * 32 + (j >> 5)) * 512 + (((j >> 3) & 3) * 16 + (b & 15)) * 8 + (j & 7);
        h_out[ofs] = __float2bfloat16(hn);
        if (h_final) h_final[cidx] = hn;
    }
}

// ---------------- projection + softmax over batch --------------------------
// grid 10 WGs (one per class) x 256 thr (one per batch col).
__global__ __launch_bounds__(256) void lstm_final(
    const float* __restrict__ Wph, const float* __restrict__ hfin,
    const float* __restrict__ bp, float* __restrict__ out)
{
    __shared__ float sh[256];
    __shared__ float shm, shs;
    int c = blockIdx.x;
    int b = threadIdx.x;
    float acc = bp[b];
    const float* wr = Wph + c * H;
    for (int k = 0; k < H; ++k)
        acc += wr[k] * hfin[k * B + b];

    sh[b] = acc;
    __syncthreads();
    for (int s = 128; s > 0; s >>= 1) {
        if (b < s) sh[b] = fmaxf(sh[b], sh[b + s]);
        __syncthreads();
    }
    if (b == 0) shm = sh[0];
    __syncthreads();
    float e = expf(acc - shm);
    sh[b] = e;
    __syncthreads();
    for (int s = 128; s > 0; s >>= 1) {
        if (b < s) sh[b] += sh[b + s];
        __syncthreads();
    }
    if (b == 0) shs = sh[0];
    __syncthreads();
    out[b * NCLS + c] = e / shs;
}

extern "C" void kernel_launch(void* const* d_in, const int* in_sizes, int n_in,
                              void* d_out, int out_size, void* d_ws, size_t ws_size,
                              hipStream_t stream)
{
    const float* x   = (const float*)d_in[0];
    const float* Wgx = (const float*)d_in[1];
    const float* Wgh = (const float*)d_in[2];
    const float* Wix = (const float*)d_in[3];
    const float* Wih = (const float*)d_in[4];
    const float* Wfx = (const float*)d_in[5];
    const float* Wfh = (const float*)d_in[6];
    const float* Wox = (const float*)d_in[7];
    const float* Woh = (const float*)d_in[8];
    const float* Wph = (const float*)d_in[9];
    const float* bg  = (const float*)d_in[10];
    const float* bi  = (const float*)d_in[11];
    const float* bfv = (const float*)d_in[12];
    const float* bo  = (const float*)d_in[13];
    const float* bp  = (const float*)d_in[14];

    char* ws = (char*)d_ws;
    __hip_bfloat16* Wsw = (__hip_bfloat16*)ws;                       // 8 MB
    __hip_bfloat16* hf0 = (__hip_bfloat16*)(ws + 8388608);           // 512 KB
    __hip_bfloat16* hf1 = (__hip_bfloat16*)(ws + 8912896);           // 512 KB
    float* cst  = (float*)(ws + 9437184);                            // 1 MB
    float* hfin = (float*)(ws + 10485760);                           // 1 MB
    // total ws use: 11534336 bytes

    hipMemsetAsync(hf0, 0, 524288, stream);
    hipMemsetAsync(cst, 0, 1048576, stream);

    prep_swizzle<<<16384, 256, 0, stream>>>(Wgh, Wih, Wfh, Woh, Wsw);

    for (int t = 0; t < T; ++t) {
        __hip_bfloat16* hin  = (t & 1) ? hf1 : hf0;
        __hip_bfloat16* hout = (t & 1) ? hf0 : hf1;
        lstm_step<<<256, 256, 0, stream>>>(Wsw, hin, hout, cst, x,
                                           Wgx, Wix, Wfx, Wox,
                                           bg, bi, bfv, bo,
                                           t, (t == T - 1) ? hfin : nullptr);
    }

    lstm_final<<<NCLS, 256, 0, stream>>>(Wph, hfin, bp, (float*)d_out);
}